// Round 3
// baseline (473.883 us; speedup 1.0000x reference)
//
#include <hip/hip_runtime.h>

// Problem constants
constexpr int NB  = 4;
constexpr int NH  = 12;
constexpr int SEQ = 1024;   // LQ == LK
constexpr int DKd = 64;
constexpr int DVd = 768;
constexpr int Ed  = 768;    // E == H*DK
constexpr int HVd = 9216;   // H*DV

typedef float f32x4 __attribute__((ext_vector_type(4)));
typedef short s16x8 __attribute__((ext_vector_type(8)));

__device__ __forceinline__ unsigned short f2bf(float f) {
  unsigned int u = __builtin_bit_cast(unsigned int, f);
  u += 0x7fffu + ((u >> 16) & 1u);          // RNE
  return (unsigned short)(u >> 16);
}

__device__ __forceinline__ float bf2f_lo(unsigned int u) {
  return __builtin_bit_cast(float, u << 16);
}
__device__ __forceinline__ float bf2f_hi(unsigned int u) {
  return __builtin_bit_cast(float, u & 0xffff0000u);
}

__device__ __forceinline__ f32x4 mfma_bf16_16x16x32(s16x8 a, s16x8 b, f32x4 c) {
  asm("v_mfma_f32_16x16x32_bf16 %0, %1, %2, %0" : "+v"(c) : "v"(a), "v"(b));
  return c;
}

#define GLOAD16(g, l)                                                          \
  __builtin_amdgcn_global_load_lds(                                            \
      (const __attribute__((address_space(1))) unsigned int*)(g),              \
      (__attribute__((address_space(3))) unsigned int*)(l), 16, 0, 0)

// ---------------------------------------------------------------------------
// v (f32) -> Vbf (bf16), elementwise
// ---------------------------------------------------------------------------
__global__ __launch_bounds__(256)
void cvt_bf16_kernel(const float* __restrict__ v, unsigned short* __restrict__ Vbf, int n4) {
  int i = blockIdx.x * 256 + threadIdx.x;
  const int stride = gridDim.x * 256;
  for (; i < n4; i += stride) {
    const f32x4 x = *(const f32x4*)&v[(size_t)i * 4];
    uint2 u;
    u.x = (unsigned)f2bf(x[0]) | ((unsigned)f2bf(x[1]) << 16);
    u.y = (unsigned)f2bf(x[2]) | ((unsigned)f2bf(x[3]) << 16);
    *(uint2*)&Vbf[(size_t)i * 4] = u;
  }
}

// ---------------------------------------------------------------------------
// ms[b][q][k] = pmask>0 ? qk_mask + k_mask : -3e38   (fused mask precompute)
// ---------------------------------------------------------------------------
__global__ __launch_bounds__(256)
void maskprep_kernel(const float* __restrict__ qk, const float* __restrict__ km,
                     const float* __restrict__ pm, float* __restrict__ ms) {
  const int i = blockIdx.x * 256 + threadIdx.x;      // f32x4 index; grid covers exactly
  const int kk4 = i & 255;                           // k chunk within row (SEQ/4)
  const int b = i >> 18;                             // i / (SEQ*SEQ/4)
  const f32x4 qv = *(const f32x4*)&qk[(size_t)i * 4];
  const f32x4 pv = *(const f32x4*)&pm[(size_t)i * 4];
  const f32x4 kv = *(const f32x4*)&km[b * SEQ + kk4 * 4];
  f32x4 o;
#pragma unroll
  for (int c = 0; c < 4; c++) o[c] = pv[c] > 0.f ? qv[c] + kv[c] : -3.0e38f;
  *(f32x4*)&ms[(size_t)i * 4] = o;
}

// ---------------------------------------------------------------------------
// Fused q/k head projections (fp32 — argmax precision path).
// 128x128 tile, BK=16, 8x8 micro-tile, grid (32,6,2) with XCD swizzle.
// ---------------------------------------------------------------------------
__global__ __launch_bounds__(256)
void qkproj_kernel(const float* __restrict__ q, const float* __restrict__ k,
                   const float* __restrict__ w_qs, const float* __restrict__ w_ks,
                   float* __restrict__ qh, float* __restrict__ kh) {
  const float* A  = blockIdx.z ? k : q;
  const float* Bw = blockIdx.z ? w_ks : w_qs;
  float* C        = blockIdx.z ? kh : qh;
  __shared__ float As[16][128];   // [k][m]
  __shared__ float Bs[16][128];   // [k][n]
  const int tid = threadIdx.x;
  const int bx = (int)blockIdx.x;
  const int sx = ((bx & 7) << 2) | (bx >> 3);        // XCD swizzle (32 m-tiles)
  const int m0 = sx * 128, n0 = blockIdx.y * 128;
  const int ty = tid >> 4, tx = tid & 15;
  const int arow = tid >> 1, akc = (tid & 1) * 8;
  const int bkr = tid >> 4, bnc = (tid & 15) * 8;

  float acc[8][8];
#pragma unroll
  for (int i = 0; i < 8; i++)
#pragma unroll
    for (int j = 0; j < 8; j++) acc[i][j] = 0.f;

  for (int k0 = 0; k0 < 768; k0 += 16) {
    const f32x4 av0 = *(const f32x4*)&A[(size_t)(m0 + arow) * 768 + k0 + akc];
    const f32x4 av1 = *(const f32x4*)&A[(size_t)(m0 + arow) * 768 + k0 + akc + 4];
    const f32x4 bv0 = *(const f32x4*)&Bw[(size_t)(k0 + bkr) * 768 + n0 + bnc];
    const f32x4 bv1 = *(const f32x4*)&Bw[(size_t)(k0 + bkr) * 768 + n0 + bnc + 4];
    __syncthreads();
#pragma unroll
    for (int c = 0; c < 4; c++) {
      As[akc + c][arow]     = av0[c];
      As[akc + 4 + c][arow] = av1[c];
    }
    *(f32x4*)&Bs[bkr][bnc]     = bv0;
    *(f32x4*)&Bs[bkr][bnc + 4] = bv1;
    __syncthreads();
#pragma unroll
    for (int kk = 0; kk < 16; kk++) {
      const f32x4 a0 = *(const f32x4*)&As[kk][ty * 8];
      const f32x4 a1 = *(const f32x4*)&As[kk][ty * 8 + 4];
      const f32x4 b0 = *(const f32x4*)&Bs[kk][tx * 8];
      const f32x4 b1 = *(const f32x4*)&Bs[kk][tx * 8 + 4];
#pragma unroll
      for (int i = 0; i < 4; i++)
#pragma unroll
        for (int j = 0; j < 4; j++) {
          acc[i][j]         += a0[i] * b0[j];
          acc[i][j + 4]     += a0[i] * b1[j];
          acc[i + 4][j]     += a1[i] * b0[j];
          acc[i + 4][j + 4] += a1[i] * b1[j];
        }
    }
  }
#pragma unroll
  for (int i = 0; i < 8; i++) {
    f32x4 o0, o1;
#pragma unroll
    for (int c = 0; c < 4; c++) { o0[c] = acc[i][c]; o1[c] = acc[i][4 + c]; }
    const size_t rb = (size_t)(m0 + ty * 8 + i) * 768 + n0 + tx * 8;
    *(f32x4*)&C[rb] = o0;
    *(f32x4*)&C[rb + 4] = o1;
  }
}

// ---------------------------------------------------------------------------
// Scores + per-128-k-block argmax: s = qh.kh/8 + ms (ms already masked).
// ---------------------------------------------------------------------------
__global__ __launch_bounds__(256)
void score_argmax_kernel(const float* __restrict__ qh, const float* __restrict__ kh,
                         const float* __restrict__ ms, float2* __restrict__ partials) {
  __shared__ float QsT[64][128];   // [d][q]
  __shared__ float KsT[64][128];   // [d][k]
  const int bh = blockIdx.z;
  const int b = bh / NH, h = bh % NH;
  const int q0 = blockIdx.y * 128;
  const int k0 = blockIdx.x * 128;
  const int tid = threadIdx.x;
  const int ty = tid >> 4, tx = tid & 15;

  const int row = tid >> 1;
  const int cb = (tid & 1) * 32;
  const float* qsrc = qh + (size_t)(b * SEQ + q0 + row) * Ed + h * DKd + cb;
  const float* ksrc = kh + (size_t)(b * SEQ + k0 + row) * Ed + h * DKd + cb;
#pragma unroll
  for (int i = 0; i < 8; i++) {
    const f32x4 qv = *(const f32x4*)&qsrc[4 * i];
    const f32x4 kv = *(const f32x4*)&ksrc[4 * i];
#pragma unroll
    for (int c = 0; c < 4; c++) {
      QsT[cb + 4 * i + c][row] = qv[c];
      KsT[cb + 4 * i + c][row] = kv[c];
    }
  }
  __syncthreads();

  float acc[8][8];
#pragma unroll
  for (int i = 0; i < 8; i++)
#pragma unroll
    for (int j = 0; j < 8; j++) acc[i][j] = 0.f;

#pragma unroll 8
  for (int kk = 0; kk < 64; kk++) {
    const f32x4 a0 = *(const f32x4*)&QsT[kk][ty * 8];
    const f32x4 a1 = *(const f32x4*)&QsT[kk][ty * 8 + 4];
    const f32x4 b0 = *(const f32x4*)&KsT[kk][tx * 8];
    const f32x4 b1 = *(const f32x4*)&KsT[kk][tx * 8 + 4];
#pragma unroll
    for (int i = 0; i < 4; i++)
#pragma unroll
      for (int j = 0; j < 4; j++) {
        acc[i][j]         += a0[i] * b0[j];
        acc[i][j + 4]     += a0[i] * b1[j];
        acc[i + 4][j]     += a1[i] * b0[j];
        acc[i + 4][j + 4] += a1[i] * b1[j];
      }
  }

  const int kg0 = k0 + tx * 8;
#pragma unroll
  for (int i = 0; i < 8; i++) {
    const int qg = q0 + ty * 8 + i;
    const size_t base = (size_t)(b * SEQ + qg) * SEQ + kg0;
    const f32x4 ms0 = *(const f32x4*)&ms[base];
    const f32x4 ms1 = *(const f32x4*)&ms[base + 4];
    float bv = -3.0e38f;
    int bi = 0;
#pragma unroll
    for (int j = 0; j < 4; j++) {
      const float s = acc[i][j] * 0.125f + ms0[j];
      if (s > bv) { bv = s; bi = kg0 + j; }
    }
#pragma unroll
    for (int j = 0; j < 4; j++) {
      const float s = acc[i][4 + j] * 0.125f + ms1[j];
      if (s > bv) { bv = s; bi = kg0 + 4 + j; }
    }
#pragma unroll
    for (int off = 1; off < 16; off <<= 1) {
      const float ov = __shfl_xor(bv, off);
      const int   oi = __shfl_xor(bi, off);
      if (ov > bv || (ov == bv && oi < bi)) { bv = ov; bi = oi; }
    }
    if (tx == 0)
      partials[(size_t)(bh * SEQ + qg) * 8 + blockIdx.x] =
          make_float2(bv, __int_as_float(bi));
  }
}

__global__ __launch_bounds__(256)
void argmax_reduce_kernel(const float2* __restrict__ partials, int* __restrict__ kmaxp) {
  const int t = blockIdx.x * 256 + threadIdx.x;
  if (t >= NB * NH * SEQ) return;
  const float2* p = partials + (size_t)t * 8;
  float bv = -3.0e38f;
  int bi = 0;
#pragma unroll
  for (int i = 0; i < 8; i++) {
    const float vv = p[i].x;
    const int ii = __float_as_int(p[i].y);
    if (vv > bv) { bv = vv; bi = ii; }
  }
  kmaxp[t] = bi;
}

// ---------------------------------------------------------------------------
// MstbT[h][n][k] = (w_vs[:,h*768:+768] @ fc[h*768:+768,:])^T  (bf16)
// ---------------------------------------------------------------------------
__global__ __launch_bounds__(256)
void wvfc_gemm_kernel(const float* __restrict__ wvs, const float* __restrict__ fcw,
                      unsigned short* __restrict__ MstbT) {
  __shared__ unsigned short As[128][72];   // [m(d)][k]  (+8 pad)
  __shared__ unsigned short Bs[128][72];   // [n][k]  (transposed B)
  const int tid = threadIdx.x;
  const int h = blockIdx.z;
  const int m0 = blockIdx.x * 128, n0 = blockIdx.y * 128;
  const int wid = tid >> 6, lane = tid & 63;
  const int wr = (wid >> 1) * 64, wc = (wid & 1) * 64;
  const int lm = lane & 15, lq = lane >> 4;
  const int ar = tid >> 1, acb = (tid & 1) * 32;
  const int br = tid >> 2, bnb = (tid & 3) * 32;

  f32x4 acc[4][4];
#pragma unroll
  for (int m = 0; m < 4; m++)
#pragma unroll
    for (int n = 0; n < 4; n++)
#pragma unroll
      for (int r = 0; r < 4; r++) acc[m][n][r] = 0.f;

  for (int k0 = 0; k0 < 768; k0 += 64) {
    const float* asrc = wvs + (size_t)(m0 + ar) * HVd + h * 768 + k0 + acb;
    const float* bsrc = fcw + (size_t)(h * 768 + k0 + br) * 768 + n0 + bnb;
    f32x4 a4[8], b4[8];
#pragma unroll
    for (int i = 0; i < 8; i++) a4[i] = *(const f32x4*)&asrc[4 * i];
#pragma unroll
    for (int i = 0; i < 8; i++) b4[i] = *(const f32x4*)&bsrc[4 * i];
    __syncthreads();
#pragma unroll
    for (int i = 0; i < 4; i++) {
      s16x8 pk;
#pragma unroll
      for (int j = 0; j < 8; j++) pk[j] = (short)f2bf(a4[2 * i + (j >> 2)][j & 3]);
      *(s16x8*)&As[ar][acb + 8 * i] = pk;
    }
#pragma unroll
    for (int i = 0; i < 8; i++)
#pragma unroll
      for (int c = 0; c < 4; c++) Bs[bnb + 4 * i + c][br] = f2bf(b4[i][c]);
    __syncthreads();
#pragma unroll
    for (int ks = 0; ks < 2; ks++) {
      s16x8 af[4], bfr[4];
#pragma unroll
      for (int m = 0; m < 4; m++)
        af[m] = *(const s16x8*)&As[wr + m * 16 + lm][ks * 32 + lq * 8];
#pragma unroll
      for (int n = 0; n < 4; n++)
        bfr[n] = *(const s16x8*)&Bs[wc + n * 16 + lm][ks * 32 + lq * 8];
#pragma unroll
      for (int m = 0; m < 4; m++)
#pragma unroll
        for (int n = 0; n < 4; n++)
          acc[m][n] = mfma_bf16_16x16x32(af[m], bfr[n], acc[m][n]);
    }
  }
  asm volatile("s_nop 7\n\ts_nop 7");
  // transposed write: MstbT[(h*768 + out_col)*768 + d], 4 consecutive d per lane (8B)
#pragma unroll
  for (int m = 0; m < 4; m++)
#pragma unroll
    for (int n = 0; n < 4; n++) {
      const int grow0 = m0 + wr + m * 16 + lq * 4;      // d (k of ugemm)
      const int gcol  = n0 + wc + n * 16 + lm;          // output col (n of ugemm)
      uint2 u;
      u.x = (unsigned)f2bf(acc[m][n][0]) | ((unsigned)f2bf(acc[m][n][1]) << 16);
      u.y = (unsigned)f2bf(acc[m][n][2]) | ((unsigned)f2bf(acc[m][n][3]) << 16);
      *(uint2*)&MstbT[(size_t)(h * 768 + gcol) * 768 + grow0] = u;
    }
}

// ---------------------------------------------------------------------------
// U[hg][4096][768p] = Vbf[4096][768] @ M_{h0+hg}  (bf16, m97-style gload_lds)
// Columns stored packed-permuted: within each 64-col chunk, short position
// p = lm*4 + n  holds actual col c = n*16 + lm  (lm=0..15, n=0..3).
// ---------------------------------------------------------------------------
__global__ __launch_bounds__(256)
void ugemm_kernel(const unsigned short* __restrict__ Vbf,
                  const unsigned short* __restrict__ MstbT,
                  unsigned short* __restrict__ U, int h0) {
  __shared__ unsigned short As[128 * 64];  // [m 128][k 64] linear
  __shared__ unsigned short Bs[128 * 64];  // [n 128][k 64] linear
  const int tid = threadIdx.x;
  const int h = h0 + blockIdx.z;
  const int bx = (int)blockIdx.x;
  const int sx = ((bx & 7) << 2) | (bx >> 3);          // XCD swizzle (32 m-tiles)
  const int m0 = sx * 128, n0 = blockIdx.y * 128;
  const int wid = tid >> 6, lane = tid & 63;
  const int wr = (wid >> 1) * 64, wc = (wid & 1) * 64;
  const int lm = lane & 15, lq = lane >> 4;
  const int srow = tid >> 3, scol = (tid & 7) * 8;     // stage: row-in-32, col
  const int ldst = (tid >> 6) * 512;                    // wave-uniform LDS base (shorts)

  const unsigned short* asrc = Vbf + (size_t)(m0 + srow) * 768 + scol;
  const unsigned short* bsrc = MstbT + (size_t)(h * 768 + n0 + srow) * 768 + scol;

  f32x4 acc[4][4];
#pragma unroll
  for (int m = 0; m < 4; m++)
#pragma unroll
    for (int n = 0; n < 4; n++)
#pragma unroll
      for (int r = 0; r < 4; r++) acc[m][n][r] = 0.f;

  for (int k0 = 0; k0 < 768; k0 += 64) {
#pragma unroll
    for (int j = 0; j < 4; j++)
      GLOAD16(asrc + (size_t)j * 32 * 768 + k0, &As[j * 2048 + ldst]);
#pragma unroll
    for (int j = 0; j < 4; j++)
      GLOAD16(bsrc + (size_t)j * 32 * 768 + k0, &Bs[j * 2048 + ldst]);
    __syncthreads();
#pragma unroll
    for (int ks = 0; ks < 2; ks++) {
      s16x8 af[4], bfr[4];
#pragma unroll
      for (int m = 0; m < 4; m++)
        af[m] = *(const s16x8*)&As[(wr + m * 16 + lm) * 64 + ks * 32 + lq * 8];
#pragma unroll
      for (int n = 0; n < 4; n++)
        bfr[n] = *(const s16x8*)&Bs[(wc + n * 16 + lm) * 64 + ks * 32 + lq * 8];
#pragma unroll
      for (int m = 0; m < 4; m++)
#pragma unroll
        for (int n = 0; n < 4; n++)
          acc[m][n] = mfma_bf16_16x16x32(af[m], bfr[n], acc[m][n]);
    }
    __syncthreads();
  }
  asm volatile("s_nop 7\n\ts_nop 7");
  const size_t urow0 = (size_t)blockIdx.z * 4096;
#pragma unroll
  for (int m = 0; m < 4; m++)
#pragma unroll
    for (int r = 0; r < 4; r++) {
      const int row = m0 + wr + m * 16 + lq * 4 + r;
      uint2 u;
      u.x = (unsigned)f2bf(acc[m][0][r]) | ((unsigned)f2bf(acc[m][1][r]) << 16);
      u.y = (unsigned)f2bf(acc[m][2][r]) | ((unsigned)f2bf(acc[m][3][r]) << 16);
      *(uint2*)&U[(urow0 + row) * 768 + n0 + wc + lm * 4] = u;
    }
}

// ---------------------------------------------------------------------------
// out0[row,:] (+)= sum_hg U[hg][kmax][:]  (+ v residual on first pass)
// One block (192 thr) per output row; inverse col-perm applied on read.
// ---------------------------------------------------------------------------
__global__ __launch_bounds__(192)
void gathersum_kernel(const unsigned short* __restrict__ U, const int* __restrict__ kmaxp,
                      const float* __restrict__ v, float* __restrict__ out0, int h0) {
  const int row = blockIdx.x;           // b*1024 + q
  const int b = row >> 10, q = row & 1023;
  const int t = threadIdx.x;            // 0..191
  float a0 = 0.f, a1 = 0.f, a2 = 0.f, a3 = 0.f;
#pragma unroll
  for (int hg = 0; hg < 6; hg++) {
    const int g = kmaxp[((b * NH + h0 + hg) << 10) + q];
    const uint2 u = *(const uint2*)&U[((size_t)hg * 4096 + (b << 10) + g) * 768 + t * 4];
    a0 += bf2f_lo(u.x);
    a1 += bf2f_hi(u.x);
    a2 += bf2f_lo(u.y);
    a3 += bf2f_hi(u.y);
  }
  const int chunk = t >> 4, lmm = t & 15;
  const size_t ob = (size_t)row * 768 + chunk * 64 + lmm;
  if (h0 == 0) {
    out0[ob +  0] = a0 + v[ob +  0];
    out0[ob + 16] = a1 + v[ob + 16];
    out0[ob + 32] = a2 + v[ob + 32];
    out0[ob + 48] = a3 + v[ob + 48];
  } else {
    out0[ob +  0] += a0;
    out0[ob + 16] += a1;
    out0[ob + 32] += a2;
    out0[ob + 48] += a3;
  }
}

__global__ void zero_kernel(f32x4* __restrict__ p, int n4) {
  int i = blockIdx.x * blockDim.x + threadIdx.x;
  const int stride = gridDim.x * blockDim.x;
  f32x4 z;
  z[0] = z[1] = z[2] = z[3] = 0.f;
  for (; i < n4; i += stride) p[i] = z;
}

__global__ __launch_bounds__(256)
void scatter_kernel(const int* __restrict__ kmaxp, float* __restrict__ attn) {
  const int t = blockIdx.x * 256 + threadIdx.x;
  if (t >= NB * NH * SEQ) return;
  attn[((size_t)t << 10) + kmaxp[t]] = 1.0f;
}

// ---------------------------------------------------------------------------
extern "C" void kernel_launch(void* const* d_in, const int* in_sizes, int n_in,
                              void* d_out, int out_size, void* d_ws, size_t ws_size,
                              hipStream_t stream) {
  (void)in_sizes; (void)n_in; (void)out_size; (void)ws_size;
  const float* q       = (const float*)d_in[0];
  const float* k       = (const float*)d_in[1];
  const float* v       = (const float*)d_in[2];
  const float* qk_mask = (const float*)d_in[5];
  const float* k_mask  = (const float*)d_in[6];
  const float* pmask   = (const float*)d_in[7];
  const float* w_qs    = (const float*)d_in[8];
  const float* w_ks    = (const float*)d_in[9];
  const float* w_vs    = (const float*)d_in[10];
  const float* fc      = (const float*)d_in[11];

  float* out0 = (float*)d_out;
  float* attn = out0 + (size_t)NB * SEQ * DVd;

  // workspace layout (58.4 MB total):
  char* ws = (char*)d_ws;
  unsigned short* MstbT = (unsigned short*)ws;                 // 14,155,776 B
  unsigned short* Vbf   = (unsigned short*)(ws + 14155776);    //  6,291,456 B
  float* msbuf          = (float*)ws;                          // 16,777,216 B — overlaps
                         // MstbT+Vbf-head; dead before cvt_bf16/wvfc run.
  int* kmaxp            = (int*)(ws + 20447232);               //    196,608 B
  char* ureg            = ws + 20643840;
  unsigned short* U     = (unsigned short*)ureg;               // 37,748,736 B
  // qh/kh/partials overlap U (dead before ugemm runs):
  float* qh             = (float*)ureg;                        // 12,582,912 B
  float* kh             = (float*)(ureg + 12582912);           // 12,582,912 B
  float2* partials      = (float2*)(ureg + 25165824);          //  3,145,728 B

  // 1) fused mask precompute (masked additive scores)
  maskprep_kernel<<<dim3(4096), 256, 0, stream>>>(qk_mask, k_mask, pmask, msbuf);

  // 2) fused q/k projections (fp32)
  qkproj_kernel<<<dim3(32, 6, 2), 256, 0, stream>>>(q, k, w_qs, w_ks, qh, kh);

  // 3) masked score argmax
  score_argmax_kernel<<<dim3(8, 8, NB * NH), 256, 0, stream>>>(qh, kh, msbuf, partials);
  argmax_reduce_kernel<<<dim3((NB * NH * SEQ + 255) / 256), 256, 0, stream>>>(partials, kmaxp);

  // 4) v -> bf16  (after argmax: Vbf overlaps msbuf tail)
  cvt_bf16_kernel<<<dim3(3072), 256, 0, stream>>>(v, Vbf, NB * SEQ * DVd / 4);

  // 5) per-head M^T = (w_vs_h @ fc_h)^T  (bf16; MstbT overlaps msbuf head)
  wvfc_gemm_kernel<<<dim3(6, 6, NH), 256, 0, stream>>>(w_vs, fc, MstbT);

  // 6) two head-groups: dense U_h = Vbf @ M_h, then gather+sum into out0
  ugemm_kernel<<<dim3(32, 6, 6), 256, 0, stream>>>(Vbf, MstbT, U, 0);
  gathersum_kernel<<<dim3(NB * SEQ), 192, 0, stream>>>(U, kmaxp, v, out0, 0);
  ugemm_kernel<<<dim3(32, 6, 6), 256, 0, stream>>>(Vbf, MstbT, U, 6);
  gathersum_kernel<<<dim3(NB * SEQ), 192, 0, stream>>>(U, kmaxp, v, out0, 6);

  // 7) attn output = one-hot(kmax)
  zero_kernel<<<dim3(2048), 256, 0, stream>>>((f32x4*)attn,
                                              (int)((size_t)NB * NH * SEQ * SEQ / 4));
  scatter_kernel<<<dim3((NB * NH * SEQ + 255) / 256), 256, 0, stream>>>(kmaxp, attn);
}

// Round 4
// 452.723 us; speedup vs baseline: 1.0467x; 1.0467x over previous
//
#include <hip/hip_runtime.h>

// Problem constants
constexpr int NB  = 4;
constexpr int NH  = 12;
constexpr int SEQ = 1024;   // LQ == LK
constexpr int DKd = 64;
constexpr int DVd = 768;
constexpr int Ed  = 768;    // E == H*DK
constexpr int HVd = 9216;   // H*DV

typedef float f32x4 __attribute__((ext_vector_type(4)));
typedef short s16x8 __attribute__((ext_vector_type(8)));

__device__ __forceinline__ unsigned short f2bf(float f) {
  unsigned int u = __builtin_bit_cast(unsigned int, f);
  u += 0x7fffu + ((u >> 16) & 1u);          // RNE
  return (unsigned short)(u >> 16);
}

__device__ __forceinline__ float bf2f_lo(unsigned int u) {
  return __builtin_bit_cast(float, u << 16);
}
__device__ __forceinline__ float bf2f_hi(unsigned int u) {
  return __builtin_bit_cast(float, u & 0xffff0000u);
}

__device__ __forceinline__ f32x4 mfma_bf16_16x16x32(s16x8 a, s16x8 b, f32x4 c) {
  asm("v_mfma_f32_16x16x32_bf16 %0, %1, %2, %0" : "+v"(c) : "v"(a), "v"(b));
  return c;
}

#define GLOAD16(g, l)                                                          \
  __builtin_amdgcn_global_load_lds(                                            \
      (const __attribute__((address_space(1))) unsigned int*)(g),              \
      (__attribute__((address_space(3))) unsigned int*)(l), 16, 0, 0)

// ---------------------------------------------------------------------------
// v (f32) -> Vbf (bf16)
// ---------------------------------------------------------------------------
__global__ __launch_bounds__(256)
void cvt_bf16_kernel(const float* __restrict__ v, unsigned short* __restrict__ Vbf, int n4) {
  int i = blockIdx.x * 256 + threadIdx.x;
  const int stride = gridDim.x * 256;
  for (; i < n4; i += stride) {
    const f32x4 x = *(const f32x4*)&v[(size_t)i * 4];
    uint2 u;
    u.x = (unsigned)f2bf(x[0]) | ((unsigned)f2bf(x[1]) << 16);
    u.y = (unsigned)f2bf(x[2]) | ((unsigned)f2bf(x[3]) << 16);
    *(uint2*)&Vbf[(size_t)i * 4] = u;
  }
}

// ---------------------------------------------------------------------------
// ms[b][q][k] = pmask>0 ? qk_mask + k_mask : -3e38
// ---------------------------------------------------------------------------
__global__ __launch_bounds__(256)
void maskprep_kernel(const float* __restrict__ qk, const float* __restrict__ km,
                     const float* __restrict__ pm, float* __restrict__ ms) {
  const int i = blockIdx.x * 256 + threadIdx.x;
  const int kk4 = i & 255;
  const int b = i >> 18;
  const f32x4 qv = *(const f32x4*)&qk[(size_t)i * 4];
  const f32x4 pv = *(const f32x4*)&pm[(size_t)i * 4];
  const f32x4 kv = *(const f32x4*)&km[b * SEQ + kk4 * 4];
  f32x4 o;
#pragma unroll
  for (int c = 0; c < 4; c++) o[c] = pv[c] > 0.f ? qv[c] + kv[c] : -3.0e38f;
  *(f32x4*)&ms[(size_t)i * 4] = o;
}

// ---------------------------------------------------------------------------
// Fused q/k head projections (fp32 — argmax precision path).
// 128x64 tile (MxN), BK=16, 8x4 micro, grid (32,12,2) = 768 blocks.
// LDS ratio: 3 b128 per 32 FMA -> VALU-bound target ~65%.
// ---------------------------------------------------------------------------
__global__ __launch_bounds__(256)
void qkproj_kernel(const float* __restrict__ q, const float* __restrict__ k,
                   const float* __restrict__ w_qs, const float* __restrict__ w_ks,
                   float* __restrict__ qh, float* __restrict__ kh) {
  const float* A  = blockIdx.z ? k : q;
  const float* Bw = blockIdx.z ? w_ks : w_qs;
  float* C        = blockIdx.z ? kh : qh;
  __shared__ float As[16][128];   // [k][m]
  __shared__ float Bs[16][64];    // [k][n]
  const int tid = threadIdx.x;
  const int m0 = blockIdx.x * 128, n0 = blockIdx.y * 64;
  const int ty = tid >> 4, tx = tid & 15;      // ty: 8-row group, tx: 4-col group
  const int arow = tid >> 1, akc = (tid & 1) * 8;
  const int bkr = tid >> 4, bnc = (tid & 15) * 4;

  float acc[8][4];
#pragma unroll
  for (int i = 0; i < 8; i++)
#pragma unroll
    for (int j = 0; j < 4; j++) acc[i][j] = 0.f;

  for (int k0 = 0; k0 < 768; k0 += 16) {
    const f32x4 av0 = *(const f32x4*)&A[(size_t)(m0 + arow) * 768 + k0 + akc];
    const f32x4 av1 = *(const f32x4*)&A[(size_t)(m0 + arow) * 768 + k0 + akc + 4];
    const f32x4 bv  = *(const f32x4*)&Bw[(size_t)(k0 + bkr) * 768 + n0 + bnc];
    __syncthreads();
#pragma unroll
    for (int c = 0; c < 4; c++) {
      As[akc + c][arow]     = av0[c];
      As[akc + 4 + c][arow] = av1[c];
    }
    *(f32x4*)&Bs[bkr][bnc] = bv;
    __syncthreads();
#pragma unroll
    for (int kk = 0; kk < 16; kk++) {
      const f32x4 a0 = *(const f32x4*)&As[kk][ty * 8];
      const f32x4 a1 = *(const f32x4*)&As[kk][ty * 8 + 4];
      const f32x4 b  = *(const f32x4*)&Bs[kk][tx * 4];
#pragma unroll
      for (int i = 0; i < 4; i++)
#pragma unroll
        for (int j = 0; j < 4; j++) {
          acc[i][j]     += a0[i] * b[j];
          acc[i + 4][j] += a1[i] * b[j];
        }
    }
  }
#pragma unroll
  for (int i = 0; i < 8; i++) {
    f32x4 o;
#pragma unroll
    for (int j = 0; j < 4; j++) o[j] = acc[i][j];
    *(f32x4*)&C[(size_t)(m0 + ty * 8 + i) * 768 + n0 + tx * 4] = o;
  }
}

// ---------------------------------------------------------------------------
// Scores + argmax, all 12 heads per block.  Block = (b, 64q x 128k).
// ms staged ONCE (32KB); per head: stage QsT(16KB)/KsT(32KB), 64-d dots,
// masked argmax partials.  Grid (8 kb, 16 qb, 4 b) = 512 blocks, 80KB LDS.
// ---------------------------------------------------------------------------
__global__ __launch_bounds__(256)
void score_argmax_kernel(const float* __restrict__ qh, const float* __restrict__ kh,
                         const float* __restrict__ ms, float2* __restrict__ partials) {
  __shared__ float msS[64][128];
  __shared__ float QsT[64][64];    // [d][q]
  __shared__ float KsT[64][128];   // [d][k]
  const int b  = blockIdx.z;
  const int q0 = blockIdx.y * 64;
  const int k0 = blockIdx.x * 128;
  const int tid = threadIdx.x;
  const int ty = tid >> 4, tx = tid & 15;

  {  // stage ms once
    const int row = tid >> 2, cc = (tid & 3) * 32;
    const float* src = ms + (size_t)(b * SEQ + q0 + row) * SEQ + k0 + cc;
#pragma unroll
    for (int i = 0; i < 8; i++)
      *(f32x4*)&msS[row][cc + 4 * i] = *(const f32x4*)&src[4 * i];
  }

  const int qr = tid >> 2, qdc = (tid & 3) * 16;
  const int kr = tid >> 1, kdc = (tid & 1) * 32;
  const float* qbase = qh + (size_t)(b * SEQ + q0 + qr) * Ed + qdc;
  const float* kbase = kh + (size_t)(b * SEQ + k0 + kr) * Ed + kdc;
  const int kg0 = k0 + tx * 8;

  for (int h = 0; h < NH; h++) {
    __syncthreads();
#pragma unroll
    for (int j = 0; j < 4; j++) {
      const f32x4 qv = *(const f32x4*)&qbase[h * 64 + 4 * j];
#pragma unroll
      for (int c = 0; c < 4; c++) QsT[qdc + 4 * j + c][qr] = qv[c];
    }
#pragma unroll
    for (int j = 0; j < 8; j++) {
      const f32x4 kv = *(const f32x4*)&kbase[h * 64 + 4 * j];
#pragma unroll
      for (int c = 0; c < 4; c++) KsT[kdc + 4 * j + c][kr] = kv[c];
    }
    __syncthreads();

    float acc[4][8];
#pragma unroll
    for (int i = 0; i < 4; i++)
#pragma unroll
      for (int j = 0; j < 8; j++) acc[i][j] = 0.f;

#pragma unroll 8
    for (int kk = 0; kk < 64; kk++) {
      const f32x4 qf  = *(const f32x4*)&QsT[kk][ty * 4];
      const f32x4 kf0 = *(const f32x4*)&KsT[kk][tx * 8];
      const f32x4 kf1 = *(const f32x4*)&KsT[kk][tx * 8 + 4];
#pragma unroll
      for (int i = 0; i < 4; i++)
#pragma unroll
        for (int j = 0; j < 4; j++) {
          acc[i][j]     += qf[i] * kf0[j];
          acc[i][j + 4] += qf[i] * kf1[j];
        }
    }

#pragma unroll
    for (int i = 0; i < 4; i++) {
      const int qg = q0 + ty * 4 + i;
      const f32x4 m0v = *(const f32x4*)&msS[ty * 4 + i][tx * 8];
      const f32x4 m1v = *(const f32x4*)&msS[ty * 4 + i][tx * 8 + 4];
      float bv = -3.0e38f;
      int bi = 0;
#pragma unroll
      for (int j = 0; j < 4; j++) {
        const float s = acc[i][j] * 0.125f + m0v[j];
        if (s > bv) { bv = s; bi = kg0 + j; }
      }
#pragma unroll
      for (int j = 0; j < 4; j++) {
        const float s = acc[i][4 + j] * 0.125f + m1v[j];
        if (s > bv) { bv = s; bi = kg0 + 4 + j; }
      }
#pragma unroll
      for (int off = 1; off < 16; off <<= 1) {
        const float ov = __shfl_xor(bv, off);
        const int   oi = __shfl_xor(bi, off);
        if (ov > bv || (ov == bv && oi < bi)) { bv = ov; bi = oi; }
      }
      if (tx == 0)
        partials[(size_t)((b * NH + h) * SEQ + qg) * 8 + blockIdx.x] =
            make_float2(bv, __int_as_float(bi));
    }
  }
}

__global__ __launch_bounds__(256)
void argmax_reduce_kernel(const float2* __restrict__ partials, int* __restrict__ kmaxp) {
  const int t = blockIdx.x * 256 + threadIdx.x;
  if (t >= NB * NH * SEQ) return;
  const float2* p = partials + (size_t)t * 8;
  float bv = -3.0e38f;
  int bi = 0;
#pragma unroll
  for (int i = 0; i < 8; i++) {
    const float vv = p[i].x;
    const int ii = __float_as_int(p[i].y);
    if (vv > bv) { bv = vv; bi = ii; }   // strict >: lowest index wins (kb ascends)
  }
  kmaxp[t] = bi;
}

// ---------------------------------------------------------------------------
// MstbT[h][n][k] = (w_vs[:,h*768:+768] @ fc[h*768:+768,:])^T  (bf16)
// ---------------------------------------------------------------------------
__global__ __launch_bounds__(256)
void wvfc_gemm_kernel(const float* __restrict__ wvs, const float* __restrict__ fcw,
                      unsigned short* __restrict__ MstbT) {
  __shared__ unsigned short As[128][72];
  __shared__ unsigned short Bs[128][72];
  const int tid = threadIdx.x;
  const int h = blockIdx.z;
  const int m0 = blockIdx.x * 128, n0 = blockIdx.y * 128;
  const int wid = tid >> 6, lane = tid & 63;
  const int wr = (wid >> 1) * 64, wc = (wid & 1) * 64;
  const int lm = lane & 15, lq = lane >> 4;
  const int ar = tid >> 1, acb = (tid & 1) * 32;
  const int br = tid >> 2, bnb = (tid & 3) * 32;

  f32x4 acc[4][4];
#pragma unroll
  for (int m = 0; m < 4; m++)
#pragma unroll
    for (int n = 0; n < 4; n++)
#pragma unroll
      for (int r = 0; r < 4; r++) acc[m][n][r] = 0.f;

  for (int k0 = 0; k0 < 768; k0 += 64) {
    const float* asrc = wvs + (size_t)(m0 + ar) * HVd + h * 768 + k0 + acb;
    const float* bsrc = fcw + (size_t)(h * 768 + k0 + br) * 768 + n0 + bnb;
    f32x4 a4[8], b4[8];
#pragma unroll
    for (int i = 0; i < 8; i++) a4[i] = *(const f32x4*)&asrc[4 * i];
#pragma unroll
    for (int i = 0; i < 8; i++) b4[i] = *(const f32x4*)&bsrc[4 * i];
    __syncthreads();
#pragma unroll
    for (int i = 0; i < 4; i++) {
      s16x8 pk;
#pragma unroll
      for (int j = 0; j < 8; j++) pk[j] = (short)f2bf(a4[2 * i + (j >> 2)][j & 3]);
      *(s16x8*)&As[ar][acb + 8 * i] = pk;
    }
#pragma unroll
    for (int i = 0; i < 8; i++)
#pragma unroll
      for (int c = 0; c < 4; c++) Bs[bnb + 4 * i + c][br] = f2bf(b4[i][c]);
    __syncthreads();
#pragma unroll
    for (int ks = 0; ks < 2; ks++) {
      s16x8 af[4], bfr[4];
#pragma unroll
      for (int m = 0; m < 4; m++)
        af[m] = *(const s16x8*)&As[wr + m * 16 + lm][ks * 32 + lq * 8];
#pragma unroll
      for (int n = 0; n < 4; n++)
        bfr[n] = *(const s16x8*)&Bs[wc + n * 16 + lm][ks * 32 + lq * 8];
#pragma unroll
      for (int m = 0; m < 4; m++)
#pragma unroll
        for (int n = 0; n < 4; n++)
          acc[m][n] = mfma_bf16_16x16x32(af[m], bfr[n], acc[m][n]);
    }
  }
  asm volatile("s_nop 7\n\ts_nop 7");
#pragma unroll
  for (int m = 0; m < 4; m++)
#pragma unroll
    for (int n = 0; n < 4; n++) {
      const int grow0 = m0 + wr + m * 16 + lq * 4;      // d (k of ugemm)
      const int gcol  = n0 + wc + n * 16 + lm;          // output col (n of ugemm)
      uint2 u;
      u.x = (unsigned)f2bf(acc[m][n][0]) | ((unsigned)f2bf(acc[m][n][1]) << 16);
      u.y = (unsigned)f2bf(acc[m][n][2]) | ((unsigned)f2bf(acc[m][n][3]) << 16);
      *(uint2*)&MstbT[(size_t)(h * 768 + gcol) * 768 + grow0] = u;
    }
}

// ---------------------------------------------------------------------------
// U[hg][4096][768p] = Vbf[4096][768] @ M_{h0+hg}  (bf16, gload_lds)
// ---------------------------------------------------------------------------
__global__ __launch_bounds__(256)
void ugemm_kernel(const unsigned short* __restrict__ Vbf,
                  const unsigned short* __restrict__ MstbT,
                  unsigned short* __restrict__ U, int h0) {
  __shared__ unsigned short As[128 * 64];
  __shared__ unsigned short Bs[128 * 64];
  const int tid = threadIdx.x;
  const int h = h0 + blockIdx.z;
  const int bx = (int)blockIdx.x;
  const int sx = ((bx & 7) << 2) | (bx >> 3);          // XCD swizzle (32 m-tiles)
  const int m0 = sx * 128, n0 = blockIdx.y * 128;
  const int wid = tid >> 6, lane = tid & 63;
  const int wr = (wid >> 1) * 64, wc = (wid & 1) * 64;
  const int lm = lane & 15, lq = lane >> 4;
  const int srow = tid >> 3, scol = (tid & 7) * 8;
  const int ldst = (tid >> 6) * 512;

  const unsigned short* asrc = Vbf + (size_t)(m0 + srow) * 768 + scol;
  const unsigned short* bsrc = MstbT + (size_t)(h * 768 + n0 + srow) * 768 + scol;

  f32x4 acc[4][4];
#pragma unroll
  for (int m = 0; m < 4; m++)
#pragma unroll
    for (int n = 0; n < 4; n++)
#pragma unroll
      for (int r = 0; r < 4; r++) acc[m][n][r] = 0.f;

  for (int k0 = 0; k0 < 768; k0 += 64) {
#pragma unroll
    for (int j = 0; j < 4; j++)
      GLOAD16(asrc + (size_t)j * 32 * 768 + k0, &As[j * 2048 + ldst]);
#pragma unroll
    for (int j = 0; j < 4; j++)
      GLOAD16(bsrc + (size_t)j * 32 * 768 + k0, &Bs[j * 2048 + ldst]);
    __syncthreads();
#pragma unroll
    for (int ks = 0; ks < 2; ks++) {
      s16x8 af[4], bfr[4];
#pragma unroll
      for (int m = 0; m < 4; m++)
        af[m] = *(const s16x8*)&As[(wr + m * 16 + lm) * 64 + ks * 32 + lq * 8];
#pragma unroll
      for (int n = 0; n < 4; n++)
        bfr[n] = *(const s16x8*)&Bs[(wc + n * 16 + lm) * 64 + ks * 32 + lq * 8];
#pragma unroll
      for (int m = 0; m < 4; m++)
#pragma unroll
        for (int n = 0; n < 4; n++)
          acc[m][n] = mfma_bf16_16x16x32(af[m], bfr[n], acc[m][n]);
    }
    __syncthreads();
  }
  asm volatile("s_nop 7\n\ts_nop 7");
  const size_t urow0 = (size_t)blockIdx.z * 4096;
#pragma unroll
  for (int m = 0; m < 4; m++)
#pragma unroll
    for (int r = 0; r < 4; r++) {
      const int row = m0 + wr + m * 16 + lq * 4 + r;
      uint2 u;
      u.x = (unsigned)f2bf(acc[m][0][r]) | ((unsigned)f2bf(acc[m][1][r]) << 16);
      u.y = (unsigned)f2bf(acc[m][2][r]) | ((unsigned)f2bf(acc[m][3][r]) << 16);
      *(uint2*)&U[(urow0 + row) * 768 + n0 + wc + lm * 4] = u;
    }
}

// ---------------------------------------------------------------------------
// out0[row,:] (+)= sum_hg U[hg][kmax][:]  (+ v residual when h0==0)
// ---------------------------------------------------------------------------
__global__ __launch_bounds__(192)
void gathersum_kernel(const unsigned short* __restrict__ U, const int* __restrict__ kmaxp,
                      const float* __restrict__ v, float* __restrict__ out0,
                      int h0, int nhg) {
  const int row = blockIdx.x;
  const int b = row >> 10, q = row & 1023;
  const int t = threadIdx.x;
  float a0 = 0.f, a1 = 0.f, a2 = 0.f, a3 = 0.f;
  for (int hg = 0; hg < nhg; hg++) {
    const int g = kmaxp[((b * NH + h0 + hg) << 10) + q];
    const uint2 u = *(const uint2*)&U[((size_t)hg * 4096 + (b << 10) + g) * 768 + t * 4];
    a0 += bf2f_lo(u.x);
    a1 += bf2f_hi(u.x);
    a2 += bf2f_lo(u.y);
    a3 += bf2f_hi(u.y);
  }
  const int chunk = t >> 4, lmm = t & 15;
  const size_t ob = (size_t)row * 768 + chunk * 64 + lmm;
  if (h0 == 0) {
    out0[ob +  0] = a0 + v[ob +  0];
    out0[ob + 16] = a1 + v[ob + 16];
    out0[ob + 32] = a2 + v[ob + 32];
    out0[ob + 48] = a3 + v[ob + 48];
  } else {
    out0[ob +  0] += a0;
    out0[ob + 16] += a1;
    out0[ob + 32] += a2;
    out0[ob + 48] += a3;
  }
}

// ---------------------------------------------------------------------------
// attn = one-hot(kmax): fused zero + scatter (each chunk decides its value)
// ---------------------------------------------------------------------------
__global__ void onehot_kernel(const int* __restrict__ kmaxp, f32x4* __restrict__ attn, int n4) {
  int i = blockIdx.x * blockDim.x + threadIdx.x;
  const int stride = gridDim.x * blockDim.x;
  for (; i < n4; i += stride) {
    const int row = i >> 8;             // 256 f32x4 chunks per 1024-row
    const int c0 = (i & 255) * 4;
    const int km = kmaxp[row];
    f32x4 o;
#pragma unroll
    for (int c = 0; c < 4; c++) o[c] = (c0 + c == km) ? 1.0f : 0.0f;
    attn[i] = o;
  }
}

// ---------------------------------------------------------------------------
extern "C" void kernel_launch(void* const* d_in, const int* in_sizes, int n_in,
                              void* d_out, int out_size, void* d_ws, size_t ws_size,
                              hipStream_t stream) {
  (void)in_sizes; (void)n_in; (void)out_size;
  const float* q       = (const float*)d_in[0];
  const float* k       = (const float*)d_in[1];
  const float* v       = (const float*)d_in[2];
  const float* qk_mask = (const float*)d_in[5];
  const float* k_mask  = (const float*)d_in[6];
  const float* pmask   = (const float*)d_in[7];
  const float* w_qs    = (const float*)d_in[8];
  const float* w_ks    = (const float*)d_in[9];
  const float* w_vs    = (const float*)d_in[10];
  const float* fc      = (const float*)d_in[11];

  float* out0 = (float*)d_out;
  float* attn = out0 + (size_t)NB * SEQ * DVd;

  // workspace layout:
  //   [MstbT 14.16M][Vbf 6.29M][kmax 0.20M][U 37.7M or 75.5M]
  //   msbuf(16.8M) overlaps MstbT+Vbf head (dead before cvt/wvfc);
  //   qh/kh/partials(28.3M) overlap U (dead before ugemm).
  char* ws = (char*)d_ws;
  unsigned short* MstbT = (unsigned short*)ws;
  unsigned short* Vbf   = (unsigned short*)(ws + 14155776);
  float* msbuf          = (float*)ws;
  int* kmaxp            = (int*)(ws + 20447232);
  char* ureg            = ws + 20643840;
  unsigned short* U     = (unsigned short*)ureg;
  float* qh             = (float*)ureg;
  float* kh             = (float*)(ureg + 12582912);
  float2* partials      = (float2*)(ureg + 25165824);

  const bool big = ws_size >= (size_t)96141312;   // room for 12-head U

  // 1) masked additive scores precompute
  maskprep_kernel<<<dim3(4096), 256, 0, stream>>>(qk_mask, k_mask, pmask, msbuf);

  // 2) fused q/k projections (fp32)
  qkproj_kernel<<<dim3(32, 12, 2), 256, 0, stream>>>(q, k, w_qs, w_ks, qh, kh);

  // 3) score + argmax, all heads per block
  score_argmax_kernel<<<dim3(8, 16, NB), 256, 0, stream>>>(qh, kh, msbuf, partials);
  argmax_reduce_kernel<<<dim3((NB * NH * SEQ + 255) / 256), 256, 0, stream>>>(partials, kmaxp);

  // 4) v -> bf16 (ms now dead)
  cvt_bf16_kernel<<<dim3(3072), 256, 0, stream>>>(v, Vbf, NB * SEQ * DVd / 4);

  // 5) per-head M^T (bf16)
  wvfc_gemm_kernel<<<dim3(6, 6, NH), 256, 0, stream>>>(w_vs, fc, MstbT);

  // 6) dense U_h = Vbf @ M_h, then gather+sum into out0
  if (big) {
    ugemm_kernel<<<dim3(32, 6, 12), 256, 0, stream>>>(Vbf, MstbT, U, 0);
    gathersum_kernel<<<dim3(NB * SEQ), 192, 0, stream>>>(U, kmaxp, v, out0, 0, 12);
  } else {
    ugemm_kernel<<<dim3(32, 6, 6), 256, 0, stream>>>(Vbf, MstbT, U, 0);
    gathersum_kernel<<<dim3(NB * SEQ), 192, 0, stream>>>(U, kmaxp, v, out0, 0, 6);
    ugemm_kernel<<<dim3(32, 6, 6), 256, 0, stream>>>(Vbf, MstbT, U, 6);
    gathersum_kernel<<<dim3(NB * SEQ), 192, 0, stream>>>(U, kmaxp, v, out0, 6, 6);
  }

  // 7) attn = one-hot(kmax)
  onehot_kernel<<<dim3(2048), 256, 0, stream>>>(kmaxp, (f32x4*)attn,
                                                (int)((size_t)NB * NH * SEQ * SEQ / 4));
}